// Round 2
// baseline (189.929 us; speedup 1.0000x reference)
//
#include <hip/hip_runtime.h>
#include <hip/hip_cooperative_groups.h>
#include <stdint.h>

namespace cg = cooperative_groups;

#define K_ELL 32      // ELL planes per near/far array (column-major)
#define K_OVF 16      // overflow planes (out-of-band fallback, expected ~empty)
#define TBS   1024
#define RNG_LOG 11
#define RNG   2048    // build window a-range
#define BAND  2048    // in-band limit on (b - v0 - 1); == RNG so unique far owner
#define RW    (RNG + BAND)   // 4096 ints = 16 KB LDS
#define MAXA  8       // register-cached a-side neighbor indices
#define MAXB  8       // register-cached b-side (ELL) neighbor indices

// adjN / adjF / adj_ovf are one contiguous allocation: plane p in [0,K_ELL) = near,
// [K_ELL,2K_ELL) = far, [2K_ELL, 2K_ELL+K_OVF) = overflow.
__device__ __forceinline__ int planeOf(int k, int kN, int kF) {
    return (k < kN) ? k
         : ((k < kN + kF) ? (K_ELL + (k - kN)) : (2 * K_ELL + (k - kN - kF)));
}

// Uncached full gather for one vertex (only used by the grid-stride safety tail
// when gridDim*TBS < V — dead code at the expected NB=256).
__device__ __forceinline__ float4 gather_one(const float4* __restrict__ x, int u,
        const int2* __restrict__ edges, const int* __restrict__ offs_a,
        const int* __restrict__ cntN, const int* __restrict__ cntF,
        const int* __restrict__ deg_ovf, const int* __restrict__ adjN, int V) {
    int aBeg = offs_a[u], aEnd = offs_a[u + 1];
    int cN = cntN[u], cF = cntF[u], dO = deg_ovf[u];
    int kN = min(cN, K_ELL), kF = min(cF, K_ELL), kO = min(dO, K_OVF);
    int kB = kN + kF + kO;
    float s0 = 0.f, s1 = 0.f, s2 = 0.f;
    for (int i = aBeg; i < aEnd; ++i) {
        float4 p = x[edges[i].y]; s0 += p.x; s1 += p.y; s2 += p.z;
    }
    for (int k = 0; k < kB; ++k) {
        float4 p = x[adjN[(size_t)planeOf(k, kN, kF) * V + u]];
        s0 += p.x; s1 += p.y; s2 += p.z;
    }
    int d = (aEnd - aBeg) + cN + cF + dO;
    float inv = 1.0f / fmaxf((float)d, 1.0f);
    return make_float4(s0 * inv, s1 * inv, s2 * inv, 0.f);
}

// One cooperative kernel: P0 prep -> P1 ELL build + faces copy -> P2 gather1
// -> P3 gather2. Thread t owns vertex u0 = t in BOTH gather rounds, so the
// neighbor-index list is cached in registers across the grid sync: round 2 is
// pure value loads (1 latency level, no index re-reads).
__global__ __launch_bounds__(TBS) void mega_kernel(
        const int2* __restrict__ edges, int* __restrict__ offs_a,
        int* __restrict__ cntN, int* __restrict__ cntF, int* __restrict__ deg_ovf,
        int* __restrict__ adjN,
        const int* __restrict__ faces, float* __restrict__ out_f,
        const float* __restrict__ v, float4* __restrict__ v4,
        float4* __restrict__ x1, float* __restrict__ out_v,
        int E, int V, int F3, int NBb) {
    cg::grid_group grid = cg::this_grid();
    const int NB = (int)gridDim.x;
    const int NT = NB * TBS;
    const int t  = (int)blockIdx.x * TBS + (int)threadIdx.x;
    __shared__ int cnt[RW];

    // ---------------- P0: offs_a + counter zeroing + v -> v4 repack ----------
    for (int i = t; i <= E; i += NT) {
        if (i < E) {
            int lo = (i == 0) ? 0 : edges[i - 1].x + 1;
            int hi = edges[i].x;
            for (int a = lo; a <= hi; ++a) offs_a[a] = i;
        } else {
            int lo = (E > 0) ? edges[E - 1].x + 1 : 0;
            for (int a = lo; a <= V; ++a) offs_a[a] = E;
        }
    }
    for (int i = t; i < V; i += NT) deg_ovf[i] = 0;
    {   // vertices with no far-owner window (u <= RNG); cntF sized V+1
        int zEnd = RNG < V ? RNG : V;
        for (int i = t; i <= zEnd; i += NT) cntF[i] = 0;
    }
    if (t == 0) cntN[0] = 0;   // vertex 0 has no near-owner window
    if (((uintptr_t)v & 15) == 0) {
        const float4* vv = (const float4*)v;
        int n4 = V >> 2;
        for (int q = t; q < n4; q += NT) {   // 3x float4 in -> 4x float4 out
            float4 a = vv[3 * q], b = vv[3 * q + 1], c = vv[3 * q + 2];
            v4[4 * q + 0] = make_float4(a.x, a.y, a.z, 0.f);
            v4[4 * q + 1] = make_float4(a.w, b.x, b.y, 0.f);
            v4[4 * q + 2] = make_float4(b.z, b.w, c.x, 0.f);
            v4[4 * q + 3] = make_float4(c.y, c.z, c.w, 0.f);
        }
        for (int u = (n4 << 2) + t; u < V; u += NT)
            v4[u] = make_float4(v[3 * u], v[3 * u + 1], v[3 * u + 2], 0.f);
    } else {
        for (int u = t; u < V; u += NT)
            v4[u] = make_float4(v[3 * u], v[3 * u + 1], v[3 * u + 2], 0.f);
    }

    grid.sync();

    // ---------------- P1: ELL transpose (blocks < NBb) + faces copy ----------
    for (int w = (int)blockIdx.x; w < NBb; w += NB) {
        const int v0   = w << RNG_LOG;
        const int vEnd = min(v0 + RNG, V);
        for (int i = threadIdx.x; i < RW; i += TBS) cnt[i] = 0;
        const int eBeg = offs_a[v0];
        const int eEnd = offs_a[vEnd];
        __syncthreads();
        for (int i = eBeg + (int)threadIdx.x; i < eEnd; i += TBS) {
            int2 e = edges[i];
            int rel = e.y - (v0 + 1);            // b > a >= v0 -> rel >= 0
            if (rel < RW) {
                int r = atomicAdd(&cnt[rel], 1); // LDS rank = final ELL slot
                if (r < K_ELL)
                    adjN[(size_t)((rel < RNG) ? r : (K_ELL + r)) * V + e.y] = e.x;
            } else {                             // rare out-of-band fallback
                int r = atomicAdd(&deg_ovf[e.y], 1);
                if (r < K_OVF) adjN[(size_t)(2 * K_ELL + r) * V + e.y] = e.x;
            }
        }
        __syncthreads();
        for (int i = threadIdx.x; i < RW; i += TBS) {
            int u = v0 + 1 + i;
            if (u < V) { if (i < RNG) cntN[u] = cnt[i]; else cntF[u] = cnt[i]; }
        }
        __syncthreads();                          // cnt reuse if multi-window
    }
    {   // faces -> float on the blocks the heavy windows leave idle
        const int cb0 = (NB > NBb) ? NBb : 0;
        if ((int)blockIdx.x >= cb0) {
            int tc = ((int)blockIdx.x - cb0) * TBS + (int)threadIdx.x;
            int TC = (NB - cb0) * TBS;
            if ((((uintptr_t)out_f | (uintptr_t)faces) & 15) == 0) {
                int n4 = F3 >> 2;
                const int4* f4 = (const int4*)faces;
                float4* o4 = (float4*)out_f;
                for (int j = tc; j < n4; j += TC) {
                    int4 a = f4[j];
                    o4[j] = make_float4((float)a.x, (float)a.y, (float)a.z, (float)a.w);
                }
                for (int j = (n4 << 2) + tc; j < F3; j += TC) out_f[j] = (float)faces[j];
            } else {
                for (int j = tc; j < F3; j += TC) out_f[j] = (float)faces[j];
            }
        }
    }

    grid.sync();

    // ---------------- P2: smoothing round 1, cache neighbor indices ---------
    int idxA[MAXA], idxB[MAXB];                  // fully-unrolled static indexing
    int da = 0, kN = 0, kF = 0, kB = 0, aBeg = 0;
    float invd = 0.f;
    const int u0 = t;
    if (u0 < V) {
        aBeg = offs_a[u0];
        int aEnd = offs_a[u0 + 1];
        int cN = cntN[u0], cF = cntF[u0], dO = deg_ovf[u0];
        da = aEnd - aBeg;
        kN = min(cN, K_ELL); kF = min(cF, K_ELL);
        int kO = min(dO, K_OVF);
        kB = kN + kF + kO;
        int dtrue = da + cN + cF + dO;           // uncapped degree = ref denominator
        invd = 1.0f / fmaxf((float)dtrue, 1.0f);
        float s0 = 0.f, s1 = 0.f, s2 = 0.f;
        #pragma unroll
        for (int j = 0; j < MAXA; ++j) {
            int g = 0;
            if (j < da) {
                g = edges[aBeg + j].y;
                float4 p = v4[g]; s0 += p.x; s1 += p.y; s2 += p.z;
            }
            idxA[j] = g;
        }
        #pragma unroll
        for (int k = 0; k < MAXB; ++k) {
            int g = 0;
            if (k < kB) {
                g = adjN[(size_t)planeOf(k, kN, kF) * V + u0];
                float4 p = v4[g]; s0 += p.x; s1 += p.y; s2 += p.z;
            }
            idxB[k] = g;
        }
        for (int j = MAXA; j < da; ++j) {        // rare high-valence tails
            float4 p = v4[edges[aBeg + j].y]; s0 += p.x; s1 += p.y; s2 += p.z;
        }
        for (int k = MAXB; k < kB; ++k) {
            float4 p = v4[adjN[(size_t)planeOf(k, kN, kF) * V + u0]];
            s0 += p.x; s1 += p.y; s2 += p.z;
        }
        x1[u0] = make_float4(s0 * invd, s1 * invd, s2 * invd, 0.f);
    }
    for (int u = t + NT; u < V; u += NT)         // safety tail (dead at NB=256)
        x1[u] = gather_one(v4, u, edges, offs_a, cntN, cntF, deg_ovf, adjN, V);

    grid.sync();

    // ---------------- P3: smoothing round 2 from cached indices -------------
    if (u0 < V) {
        float s0 = 0.f, s1 = 0.f, s2 = 0.f;
        #pragma unroll
        for (int j = 0; j < MAXA; ++j)
            if (j < da) { float4 p = x1[idxA[j]]; s0 += p.x; s1 += p.y; s2 += p.z; }
        #pragma unroll
        for (int k = 0; k < MAXB; ++k)
            if (k < kB) { float4 p = x1[idxB[k]]; s0 += p.x; s1 += p.y; s2 += p.z; }
        for (int j = MAXA; j < da; ++j) {
            float4 p = x1[edges[aBeg + j].y]; s0 += p.x; s1 += p.y; s2 += p.z;
        }
        for (int k = MAXB; k < kB; ++k) {
            float4 p = x1[adjN[(size_t)planeOf(k, kN, kF) * V + u0]];
            s0 += p.x; s1 += p.y; s2 += p.z;
        }
        out_v[3 * u0 + 0] = s0 * invd;
        out_v[3 * u0 + 1] = s1 * invd;
        out_v[3 * u0 + 2] = s2 * invd;
    }
    for (int u = t + NT; u < V; u += NT) {       // safety tail (dead at NB=256)
        float4 r = gather_one(x1, u, edges, offs_a, cntN, cntF, deg_ovf, adjN, V);
        out_v[3 * u + 0] = r.x; out_v[3 * u + 1] = r.y; out_v[3 * u + 2] = r.z;
    }
}

extern "C" void kernel_launch(void* const* d_in, const int* in_sizes, int n_in,
                              void* d_out, int out_size, void* d_ws, size_t ws_size,
                              hipStream_t stream) {
    const float* v     = (const float*)d_in[0];  // [V,3]
    const int2*  edges = (const int2*)d_in[1];   // [E,2], rows lex-sorted, a<b
    const int*   faces = (const int*)d_in[2];    // [F,3]

    const int V3 = in_sizes[0];
    const int V  = V3 / 3;
    const int E  = in_sizes[1] / 2;
    const int F3 = in_sizes[2];

    float* out_v = (float*)d_out;
    float* out_f = (float*)d_out + V3;

    // ws layout (16B-aligned float4 arrays first): v4[V] | x1[V] |
    //   adj[(2*K_ELL+K_OVF)*V] (near|far|ovf contiguous) | offs_a[V+1] |
    //   cntN[V+1] | cntF[V+1] | deg_ovf[V]
    float4* v4      = (float4*)d_ws;
    float4* x1      = v4 + V;
    int*    adjN    = (int*)(x1 + V);
    int*    offs_a  = adjN + (size_t)(2 * K_ELL + K_OVF) * V;
    int*    cntN    = offs_a + (V + 1);
    int*    cntF    = cntN + (V + 1);
    int*    deg_ovf = cntF + (V + 1);

    const int NBb = (V + RNG - 1) / RNG;          // heavy ELL windows (~91)

    // Co-residency bound for the cooperative launch (cached; host-only queries).
    static int nbMax = -1;
    if (nbMax < 0) {
        int occ = 0, cus = 0, dev = 0;
        (void)hipGetDevice(&dev);
        (void)hipOccupancyMaxActiveBlocksPerMultiprocessor(
                &occ, (const void*)mega_kernel, TBS, 0);
        (void)hipDeviceGetAttribute(&cus, hipDeviceAttributeMultiprocessorCount, dev);
        if (occ < 1) occ = 1;
        if (cus < 1) cus = 256;
        nbMax = occ * cus;
    }
    int NB = nbMax < 256 ? nbMax : 256;           // 256*1024 threads >= V

    void* args[] = { (void*)&edges, (void*)&offs_a, (void*)&cntN, (void*)&cntF,
                     (void*)&deg_ovf, (void*)&adjN, (void*)&faces, (void*)&out_f,
                     (void*)&v, (void*)&v4, (void*)&x1, (void*)&out_v,
                     (void*)&E, (void*)&V, (void*)&F3, (void*)&NBb };
    (void)hipLaunchCooperativeKernel((const void*)mega_kernel, dim3(NB), dim3(TBS),
                                     args, 0, stream);
}

// Round 3
// 86.517 us; speedup vs baseline: 2.1953x; 2.1953x over previous
//
#include <hip/hip_runtime.h>
#include <stdint.h>

#define K_ELL 32      // ELL planes per near/far array (column-major; untouched planes = 0 traffic)
#define K_OVF 16      // overflow planes (out-of-band fallback, expected ~empty)
#define TBS   1024    // build block size
#define RNG_LOG 11
#define RNG   2048    // build block a-range
#define BAND  2048    // in-band limit on (b - v0 - 1); == RNG so each vertex has unique far owner
#define RW    (RNG + BAND)   // 4096 ints = 16 KB LDS
#define BS    256
#define UA    6       // unrolled a-side slots (index loads hoisted, branchless)
#define UN    6       // unrolled near-ELL slots
#define UF    4       // unrolled far-ELL slots

// prep (light): offs_a[u] = first edge index with edges[.].x >= u (edges[:,0] sorted
// asc, a<b, from np.unique(np.sort(e,1),axis=0)); zero the counters build's LDS
// dumps don't cover (deg_ovf, cntF[0..RNG], cntN[0]).
__global__ void prep_kernel(const int2* __restrict__ edges, int* __restrict__ offs_a,
                            int* __restrict__ cntN, int* __restrict__ cntF,
                            int* __restrict__ deg_ovf, int E, int V) {
    int i = blockIdx.x * blockDim.x + threadIdx.x;
    if (i <= E) {
        if (i < E) {
            int lo = (i == 0) ? 0 : edges[i - 1].x + 1;
            int hi = edges[i].x;
            for (int a = lo; a <= hi; a++) offs_a[a] = i;
        } else {
            for (int a = edges[E - 1].x + 1; a <= V; a++) offs_a[a] = E;
        }
    }
    if (i < V) deg_ovf[i] = 0;
    if (i <= RNG) cntF[i] = 0;   // vertices with no far-owner block
    if (i == 0) cntN[0] = 0;     // vertex 0 has no near-owner block
}

// build: heavy blocks (< NBb) do the b-side transpose via LDS-rank atomics into
// column-major near/far ELL; copy blocks (>= NBb) do faces->float (int4/float4
// vectorized) and v->float4 repack on the ~165 CUs the heavy blocks leave idle.
__global__ __launch_bounds__(TBS) void build_kernel(
        const int2* __restrict__ edges, const int* __restrict__ offs_a,
        int* __restrict__ cntN, int* __restrict__ cntF, int* __restrict__ deg_ovf,
        int* __restrict__ adjN, int* __restrict__ adjF, int* __restrict__ adj_ovf,
        const int* __restrict__ faces, float* __restrict__ out_f,
        const float* __restrict__ v, float4* __restrict__ v4,
        int E, int V, int F3, int NBb) {
    if ((int)blockIdx.x >= NBb) {
        int t = (blockIdx.x - NBb) * TBS + threadIdx.x;
        int T = (gridDim.x - NBb) * TBS;
        if ((((uintptr_t)out_f | (uintptr_t)faces) & 15) == 0) {
            int n4 = F3 >> 2;
            const int4* f4 = (const int4*)faces;
            float4* o4 = (float4*)out_f;
            for (int j = t; j < n4; j += T) {
                int4 a = f4[j];
                o4[j] = make_float4((float)a.x, (float)a.y, (float)a.z, (float)a.w);
            }
            for (int j = (n4 << 2) + t; j < F3; j += T) out_f[j] = (float)faces[j];
        } else {
            for (int j = t; j < F3; j += T) out_f[j] = (float)faces[j];
        }
        if (((uintptr_t)v & 15) == 0) {
            const float4* vv = (const float4*)v;
            int n4v = V >> 2;
            for (int q = t; q < n4v; q += T) {   // 3x float4 in -> 4x float4 out
                float4 a = vv[3 * q], b = vv[3 * q + 1], c = vv[3 * q + 2];
                v4[4 * q + 0] = make_float4(a.x, a.y, a.z, 0.f);
                v4[4 * q + 1] = make_float4(a.w, b.x, b.y, 0.f);
                v4[4 * q + 2] = make_float4(b.z, b.w, c.x, 0.f);
                v4[4 * q + 3] = make_float4(c.y, c.z, c.w, 0.f);
            }
            for (int u = (n4v << 2) + t; u < V; u += T)
                v4[u] = make_float4(v[3 * u], v[3 * u + 1], v[3 * u + 2], 0.f);
        } else {
            for (int u = t; u < V; u += T)
                v4[u] = make_float4(v[3 * u], v[3 * u + 1], v[3 * u + 2], 0.f);
        }
        return;
    }
    __shared__ int cnt[RW];
    const int v0   = blockIdx.x << RNG_LOG;
    const int vEnd = min(v0 + RNG, V);
    for (int i = threadIdx.x; i < RW; i += TBS) cnt[i] = 0;
    const int eBeg = offs_a[v0];
    const int eEnd = offs_a[vEnd];
    __syncthreads();
    for (int i = eBeg + threadIdx.x; i < eEnd; i += TBS) {
        int2 e = edges[i];
        int rel = e.y - (v0 + 1);            // b > a >= v0 -> rel >= 0
        if (rel < RW) {
            int r = atomicAdd(&cnt[rel], 1); // LDS rank = final ELL slot
            if (rel < RNG) { if (r < K_ELL) adjN[(size_t)r * V + e.y] = e.x; }
            else           { if (r < K_ELL) adjF[(size_t)r * V + e.y] = e.x; }
        } else {                              // out-of-band fallback (rare; always correct)
            int r = atomicAdd(&deg_ovf[e.y], 1);
            if (r < K_OVF) adj_ovf[(size_t)r * V + e.y] = e.x;
        }
    }
    __syncthreads();
    for (int i = threadIdx.x; i < RW; i += TBS) {
        int u = v0 + 1 + i;
        if (u < V) {
            if (i < RNG) cntN[u] = cnt[i];   // unique near owner
            else         cntF[u] = cnt[i];   // unique far owner (BAND == RNG)
        }
    }
}

// gather: lambd==1 -> y = nbr_sum/deg (deg==0 -> 0, matches ref).
// Latency-level-compressed: level 1 = counts/offsets, level 2 = ALL index loads
// (branchless: a-side addresses min-clamped to E-1, ELL planes read
// unconditionally in-bounds), level 3 = ALL value loads, empty slots killed by
// m*p (adds +0.0 -> bit-exact, accumulation order == old kernel's). Tails keep
// the old a->near->far->ovf order for vertices exceeding the unroll caps.
template <bool PAD>
__global__ void gather_kernel(const float4* __restrict__ x4, const int2* __restrict__ edges,
                              const int* __restrict__ offs_a,
                              const int* __restrict__ cntN, const int* __restrict__ cntF,
                              const int* __restrict__ deg_ovf,
                              const int* __restrict__ adjN, const int* __restrict__ adjF,
                              const int* __restrict__ adj_ovf,
                              float* __restrict__ y, int V, int E) {
    int u = blockIdx.x * blockDim.x + threadIdx.x;
    if (u >= V) return;
    int aBeg = offs_a[u], aEnd = offs_a[u + 1];
    int cN = cntN[u], cF = cntF[u], dO = deg_ovf[u];
    int da = aEnd - aBeg;
    int kN = cN > K_ELL ? K_ELL : cN;
    int kF = cF > K_ELL ? K_ELL : cF;
    // ---- level 2: all neighbor-index loads issue together (no branches) ----
    int gA[UA], gN[UN], gF[UF];
    #pragma unroll
    for (int j = 0; j < UA; ++j) gA[j] = edges[min(aBeg + j, E - 1)].y;  // in-bounds
    #pragma unroll
    for (int k = 0; k < UN; ++k) gN[k] = adjN[(size_t)k * V + u];        // plane read, in-bounds
    #pragma unroll
    for (int k = 0; k < UF; ++k) gF[k] = adjF[(size_t)k * V + u];
    // ---- level 3: value loads, mask-multiplied; order == old sequential ----
    float s0 = 0.f, s1 = 0.f, s2 = 0.f;
    #pragma unroll
    for (int j = 0; j < UA; ++j) {
        float m = (j < da) ? 1.f : 0.f;                // gA valid index even if j>=da
        float4 p = x4[gA[j]];
        s0 += m * p.x; s1 += m * p.y; s2 += m * p.z;
    }
    for (int j = UA; j < da; ++j) {                    // rare high-valence tail
        float4 p = x4[edges[aBeg + j].y];
        s0 += p.x; s1 += p.y; s2 += p.z;
    }
    #pragma unroll
    for (int k = 0; k < UN; ++k) {
        float m = (k < kN) ? 1.f : 0.f;
        float4 p = x4[(k < kN) ? gN[k] : 0];           // clamp: slot may hold poison
        s0 += m * p.x; s1 += m * p.y; s2 += m * p.z;
    }
    for (int k = UN; k < kN; ++k) {
        float4 p = x4[adjN[(size_t)k * V + u]];
        s0 += p.x; s1 += p.y; s2 += p.z;
    }
    #pragma unroll
    for (int k = 0; k < UF; ++k) {
        float m = (k < kF) ? 1.f : 0.f;
        float4 p = x4[(k < kF) ? gF[k] : 0];
        s0 += m * p.x; s1 += m * p.y; s2 += m * p.z;
    }
    for (int k = UF; k < kF; ++k) {
        float4 p = x4[adjF[(size_t)k * V + u]];
        s0 += p.x; s1 += p.y; s2 += p.z;
    }
    int kO = dO > K_OVF ? K_OVF : dO;
    for (int k = 0; k < kO; ++k) {                     // expected empty
        float4 p = x4[adj_ovf[(size_t)k * V + u]];
        s0 += p.x; s1 += p.y; s2 += p.z;
    }
    int d = da + cN + cF + dO;
    float inv = 1.0f / fmaxf((float)d, 1.0f);
    if (PAD) {
        ((float4*)y)[u] = make_float4(s0 * inv, s1 * inv, s2 * inv, 0.f);
    } else {
        y[3 * u + 0] = s0 * inv;
        y[3 * u + 1] = s1 * inv;
        y[3 * u + 2] = s2 * inv;
    }
}

extern "C" void kernel_launch(void* const* d_in, const int* in_sizes, int n_in,
                              void* d_out, int out_size, void* d_ws, size_t ws_size,
                              hipStream_t stream) {
    const float* v     = (const float*)d_in[0];  // [V,3]
    const int2*  edges = (const int2*)d_in[1];   // [E,2], rows lex-sorted, a<b
    const int*   faces = (const int*)d_in[2];    // [F,3]

    const int V3 = in_sizes[0];
    const int V  = V3 / 3;
    const int E  = in_sizes[1] / 2;
    const int F3 = in_sizes[2];

    float* out_v = (float*)d_out;
    float* out_f = (float*)d_out + V3;

    // ws layout (16B-aligned float4 arrays first): v4[V] | x1[V] | adjN[K_ELL*V] |
    //   adjF[K_ELL*V] | adj_ovf[K_OVF*V] | offs_a[V+1] | cntN[V+1] | cntF[V+1] | deg_ovf[V]
    float4* v4      = (float4*)d_ws;
    float4* x1      = v4 + V;
    int*    adjN    = (int*)(x1 + V);
    int*    adjF    = adjN + (size_t)K_ELL * V;
    int*    adj_ovf = adjF + (size_t)K_ELL * V;
    int*    offs_a  = adj_ovf + (size_t)K_OVF * V;
    int*    cntN    = offs_a + (V + 1);
    int*    cntF    = cntN + (V + 1);
    int*    deg_ovf = cntF + (V + 1);

    const int NBb = (V + RNG - 1) / RNG;          // heavy build blocks (~91)
    const int copyElems = F3 > V ? F3 : V;
    const int NBc = (copyElems + TBS - 1) / TBS;  // copy blocks (~1086)
    const int gP  = (E + 1 + BS - 1) / BS;        // prep covers edges (+V zeroing folded)
    const int gV  = (V + BS - 1) / BS;

    prep_kernel<<<gP, BS, 0, stream>>>(edges, offs_a, cntN, cntF, deg_ovf, E, V);

    build_kernel<<<NBb + NBc, TBS, 0, stream>>>(edges, offs_a, cntN, cntF, deg_ovf,
                                                adjN, adjF, adj_ovf, faces, out_f,
                                                v, v4, E, V, F3, NBb);

    gather_kernel<true ><<<gV, BS, 0, stream>>>(v4, edges, offs_a, cntN, cntF, deg_ovf,
                                                adjN, adjF, adj_ovf, (float*)x1, V, E);
    gather_kernel<false><<<gV, BS, 0, stream>>>(x1, edges, offs_a, cntN, cntF, deg_ovf,
                                                adjN, adjF, adj_ovf, out_v, V, E);
}